// Round 1
// baseline (366.434 us; speedup 1.0000x reference)
//
#include <hip/hip_runtime.h>
#include <hip/hip_bf16.h>

// Problem constants
#define BT_ 1
#define N_  4
#define C_  64
#define H_  28
#define W_  60
#define ZC_ 200
#define YC_ 8
#define XC_ 200
#define OUTC_ 128
#define KD_ 512            // C_*YC_
#define EPS_ 1e-6f

#define TX 8               // x positions per block

// ---------------------------------------------------------------------------
// Prep: featT[n][h][w][c] = img[n][c][h][w]   (channels-last for coalesced gathers)
//       Wp[o][y*64+c]     = W[o][c*8+y]      (y-major k to match LDS red layout)
// ---------------------------------------------------------------------------
__global__ void gsvt_prep(const float* __restrict__ img,
                          const float* __restrict__ Wc,
                          float* __restrict__ featT,
                          float* __restrict__ Wp) {
    int tid = blockIdx.x * blockDim.x + threadIdx.x;
    int stride = gridDim.x * blockDim.x;
    const int totF = N_ * H_ * W_ * C_;       // 430080
    for (int i = tid; i < totF; i += stride) {
        int c = i & 63;
        int w = (i >> 6) % W_;
        int h = ((i >> 6) / W_) % H_;
        int n = (i >> 6) / (W_ * H_);
        featT[i] = img[((n * C_ + c) * H_ + h) * W_ + w];
    }
    const int totW = OUTC_ * KD_;             // 65536
    for (int i = tid; i < totW; i += stride) {
        int k = i & (KD_ - 1);
        int o = i >> 9;
        int y = k >> 6;       // 0..7
        int c = k & 63;       // 0..63
        Wp[i] = Wc[o * KD_ + c * YC_ + y];
    }
}

// ---------------------------------------------------------------------------
// Fused: sample + masked mean over cameras + 512->128 matvec
// Grid: (XC_/TX, ZC_), block 256
// ---------------------------------------------------------------------------
__global__ __launch_bounds__(256) void gsvt_fused(
        const float* __restrict__ coords,   // (N, ZC, YC, XC, 3)
        const float* __restrict__ validm,   // (N, ZC, YC, XC)
        const float* __restrict__ featT,    // (N, H, W, C)
        const float* __restrict__ Wp,       // (OUTC, 512) y-major k
        const float* __restrict__ bias,     // (OUTC)
        float* __restrict__ out)            // (OUTC, ZC, XC)
{
    __shared__ float red[TX][KD_];

    const int z  = blockIdx.y;
    const int x0 = blockIdx.x * TX;
    const int t  = threadIdx.x;

    // ---------------- Phase 1: sampling ----------------
    // 16 groups of 16 lanes; each group owns (xl, y) pairs p = grp, grp+16, ...
    const int grp    = t >> 4;   // 0..15
    const int lane16 = t & 15;   // 0..15

    for (int p = grp; p < TX * YC_; p += 16) {
        const int xl = p >> 3;   // 0..TX-1
        const int y  = p & 7;    // 0..7
        const int xg = x0 + xl;

        float num0 = 0.f, num1 = 0.f, num2 = 0.f, num3 = 0.f;
        float den = 0.f;

        #pragma unroll
        for (int n = 0; n < N_; ++n) {
            const int cbase = (((n * ZC_ + z) * YC_ + y) * XC_ + xg);
            const float gx = coords[cbase * 3 + 0];
            const float gy = coords[cbase * 3 + 1];
            const float gz = coords[cbase * 3 + 2];
            const float m  = validm[cbase];

            const float xf = ((gx + 1.0f) * (float)W_ - 1.0f) * 0.5f;
            const float yf = ((gy + 1.0f) * (float)H_ - 1.0f) * 0.5f;
            const float zf = gz * 0.5f;

            const float x0f = floorf(xf), y0f = floorf(yf), z0f = floorf(zf);
            const float wx = xf - x0f, wy = yf - y0f, wz = zf - z0f;
            const int xi0 = (int)x0f, yi0 = (int)y0f, zi0 = (int)z0f;

            // D=1: only depth slice 0 exists; z-weight per reference semantics
            const float zw = (zi0 == 0) ? (1.f - wz) : ((zi0 == -1) ? wz : 0.f);
            const float mzw = m * zw;

            #pragma unroll
            for (int dy = 0; dy < 2; ++dy) {
                const int yi = yi0 + dy;
                const float wyv = dy ? wy : (1.f - wy);
                const bool yok = (yi >= 0) && (yi < H_);
                #pragma unroll
                for (int dx = 0; dx < 2; ++dx) {
                    const int xi = xi0 + dx;
                    const float wxv = dx ? wx : (1.f - wx);
                    const bool ok = yok && (xi >= 0) && (xi < W_);
                    const float wgt = ok ? (mzw * wyv * wxv) : 0.f;
                    const int yc = ok ? yi : 0;
                    const int xc = ok ? xi : 0;
                    const float4 v = *(const float4*)(featT
                            + (((n * H_ + yc) * W_ + xc) << 6) + (lane16 << 2));
                    num0 += wgt * v.x;
                    num1 += wgt * v.y;
                    num2 += wgt * v.z;
                    num3 += wgt * v.w;
                }
            }
            den += m;
        }

        const float inv = 1.0f / (den + EPS_);
        float4 r4;
        r4.x = num0 * inv; r4.y = num1 * inv; r4.z = num2 * inv; r4.w = num3 * inv;
        *(float4*)&red[xl][(y << 6) + (lane16 << 2)] = r4;
    }

    __syncthreads();

    // ---------------- Phase 2: matvec 512 -> 128 ----------------
    const int o  = t & 127;      // output channel
    const int xh = t >> 7;       // half of the x tile (0/1)

    float acc0 = 0.f, acc1 = 0.f, acc2 = 0.f, acc3 = 0.f;
    const float* wrow = Wp + o * KD_;

    for (int k = 0; k < KD_; k += 4) {
        const float4 wv = *(const float4*)(wrow + k);
        const float4 r0 = *(const float4*)&red[xh * 4 + 0][k];
        const float4 r1 = *(const float4*)&red[xh * 4 + 1][k];
        const float4 r2 = *(const float4*)&red[xh * 4 + 2][k];
        const float4 r3 = *(const float4*)&red[xh * 4 + 3][k];
        acc0 += wv.x * r0.x + wv.y * r0.y + wv.z * r0.z + wv.w * r0.w;
        acc1 += wv.x * r1.x + wv.y * r1.y + wv.z * r1.z + wv.w * r1.w;
        acc2 += wv.x * r2.x + wv.y * r2.y + wv.z * r2.z + wv.w * r2.w;
        acc3 += wv.x * r3.x + wv.y * r3.y + wv.z * r3.z + wv.w * r3.w;
    }

    const float b = bias[o];
    const int obase = (o * ZC_ + z) * XC_ + x0 + xh * 4;
    out[obase + 0] = acc0 + b;
    out[obase + 1] = acc1 + b;
    out[obase + 2] = acc2 + b;
    out[obase + 3] = acc3 + b;
}

extern "C" void kernel_launch(void* const* d_in, const int* in_sizes, int n_in,
                              void* d_out, int out_size, void* d_ws, size_t ws_size,
                              hipStream_t stream) {
    const float* coords = (const float*)d_in[0];   // (1,4,200,8,200,3)
    const float* validm = (const float*)d_in[1];   // (1,4,200,8,200,1)
    const float* img    = (const float*)d_in[2];   // (1,4,64,28,60)
    const float* Wc     = (const float*)d_in[3];   // (128, 512)
    const float* bias   = (const float*)d_in[4];   // (128)
    float* out = (float*)d_out;                    // (1,1,128,200,200)

    float* featT = (float*)d_ws;                   // 430080 floats
    float* Wp    = featT + (N_ * H_ * W_ * C_);    // 65536 floats

    gsvt_prep<<<512, 256, 0, stream>>>(img, Wc, featT, Wp);

    dim3 grid(XC_ / TX, ZC_);
    gsvt_fused<<<grid, 256, 0, stream>>>(coords, validm, featT, Wp, bias, out);
}

// Round 2
// 93.214 us; speedup vs baseline: 3.9311x; 3.9311x over previous
//
#include <hip/hip_runtime.h>
#include <hip/hip_bf16.h>

#define N_  4
#define C_  64
#define H_  28
#define W_  60
#define ZC_ 200
#define YC_ 8
#define XC_ 200
#define OUTC_ 128
#define KD_ 512            // C_*YC_
#define EPS_ 1e-6f
#define TX 16              // x positions per block (one MFMA N-tile)

typedef __attribute__((ext_vector_type(8))) short short8;
typedef __attribute__((ext_vector_type(4))) float f32x4;

__device__ __forceinline__ unsigned short f2bf(float f) {
    unsigned int u = __float_as_uint(f);
    u += 0x7FFF + ((u >> 16) & 1);   // round-to-nearest-even
    return (unsigned short)(u >> 16);
}

// ---------------------------------------------------------------------------
// Prep: featB[n][h][w][c] = bf16(img[n][c][h][w])  (channels-last, bf16)
//       Wb[o][y*64+c]     = bf16(W[o][c*8+y])      (y-major k, bf16)
// ---------------------------------------------------------------------------
__global__ void gsvt_prep(const float* __restrict__ img,
                          const float* __restrict__ Wc,
                          unsigned short* __restrict__ featB,
                          unsigned short* __restrict__ Wb) {
    int tid = blockIdx.x * blockDim.x + threadIdx.x;
    int stride = gridDim.x * blockDim.x;
    const int totF = N_ * H_ * W_ * C_;       // 430080
    for (int i = tid; i < totF; i += stride) {
        int c  = i & 63;
        int hw = i >> 6;
        int w  = hw % W_;
        int nh = hw / W_;
        int h  = nh % H_;
        int n  = nh / H_;
        featB[i] = f2bf(img[((n * C_ + c) * H_ + h) * W_ + w]);
    }
    const int totW = OUTC_ * KD_;             // 65536
    for (int i = tid; i < totW; i += stride) {
        int k = i & (KD_ - 1);
        int o = i >> 9;
        int y = k >> 6;
        int c = k & 63;
        Wb[i] = f2bf(Wc[o * KD_ + c * YC_ + y]);
    }
}

// ---------------------------------------------------------------------------
// Fused: sample + masked mean over cameras + 512->128 MFMA matvec
// Grid: (ceil(XC/TX)=13, ZC), block 256
// ---------------------------------------------------------------------------
__global__ __launch_bounds__(256) void gsvt_fused(
        const float* __restrict__ coords,        // (N, ZC, YC, XC, 3)
        const float* __restrict__ validm,        // (N, ZC, YC, XC)
        const unsigned short* __restrict__ featB,// (N, H, W, C) bf16
        const unsigned short* __restrict__ Wb,   // (OUTC, 512) bf16, y-major k
        const float* __restrict__ bias,          // (OUTC)
        float* __restrict__ out)                 // (OUTC, ZC, XC)
{
    __shared__ float cs[N_][YC_][TX][4];              // (gx,gy,gz,m) = 8 KB
    __shared__ unsigned short redB[64][TX][8];        // k-blocked bf16, 16 KB

    const int z  = blockIdx.y;
    const int x0 = blockIdx.x * TX;
    const int t  = threadIdx.x;

    // ---- Stage coords + mask into LDS (coalesced-ish, clamped at x=199) ----
    for (int idx = t; idx < N_ * YC_ * TX * 3; idx += 256) {   // 1536
        int row  = idx / 48;              // n*8+y
        int j    = idx - row * 48;
        int xl   = j / 3;
        int comp = j - xl * 3;
        int n = row >> 3, y = row & 7;
        int xg = min(x0 + xl, XC_ - 1);
        cs[n][y][xl][comp] =
            coords[((size_t)((n * ZC_ + z) * YC_ + y) * XC_ + xg) * 3 + comp];
    }
    for (int idx = t; idx < N_ * YC_ * TX; idx += 256) {       // 512
        int n = idx >> 7, y = (idx >> 4) & 7, xl = idx & 15;
        int xg = min(x0 + xl, XC_ - 1);
        cs[n][y][xl][3] = validm[((n * ZC_ + z) * YC_ + y) * XC_ + xg];
    }
    __syncthreads();

    // ---- Phase 1: sampling. 32 groups of 8 lanes; each lane owns 8 channels ----
    const int grp   = t >> 3;   // 0..31
    const int lane8 = t & 7;    // 0..7 -> channels lane8*8 .. +7

    for (int p = grp; p < TX * YC_; p += 32) {   // 128 (x,y) pairs
        const int xl = p >> 3;
        const int y  = p & 7;

        float num[8] = {0.f,0.f,0.f,0.f,0.f,0.f,0.f,0.f};
        float den = 0.f;

        #pragma unroll
        for (int n = 0; n < N_; ++n) {
            const float4 cm = *(const float4*)&cs[n][y][xl][0];
            const float m = cm.w;

            const float xf = ((cm.x + 1.0f) * (float)W_ - 1.0f) * 0.5f;
            const float yf = ((cm.y + 1.0f) * (float)H_ - 1.0f) * 0.5f;
            const float zf = cm.z * 0.5f;

            const float x0f = floorf(xf), y0f = floorf(yf), z0f = floorf(zf);
            const float wx = xf - x0f, wy = yf - y0f, wz = zf - z0f;
            const int xi0 = (int)x0f, yi0 = (int)y0f, zi0 = (int)z0f;

            const float zw = (zi0 == 0) ? (1.f - wz) : ((zi0 == -1) ? wz : 0.f);
            const float mzw = m * zw;

            #pragma unroll
            for (int dy = 0; dy < 2; ++dy) {
                const int yi = yi0 + dy;
                const float wyv = dy ? wy : (1.f - wy);
                const bool yok = (yi >= 0) && (yi < H_);
                #pragma unroll
                for (int dx = 0; dx < 2; ++dx) {
                    const int xi = xi0 + dx;
                    const float wxv = dx ? wx : (1.f - wx);
                    const bool ok = yok && (xi >= 0) && (xi < W_);
                    const float wgt = ok ? (mzw * wyv * wxv) : 0.f;
                    const int yc = ok ? yi : 0;
                    const int xc = ok ? xi : 0;
                    const uint4 V = *(const uint4*)(featB
                            + (((n * H_ + yc) * W_ + xc) << 6) + (lane8 << 3));
                    num[0] += wgt * __uint_as_float(V.x << 16);
                    num[1] += wgt * __uint_as_float(V.x & 0xFFFF0000u);
                    num[2] += wgt * __uint_as_float(V.y << 16);
                    num[3] += wgt * __uint_as_float(V.y & 0xFFFF0000u);
                    num[4] += wgt * __uint_as_float(V.z << 16);
                    num[5] += wgt * __uint_as_float(V.z & 0xFFFF0000u);
                    num[6] += wgt * __uint_as_float(V.w << 16);
                    num[7] += wgt * __uint_as_float(V.w & 0xFFFF0000u);
                }
            }
            den += m;
        }

        const float inv = 1.0f / (den + EPS_);
        // k = y*64 + lane8*8 + j  ->  kb = y*8+lane8, elem j contiguous
        const int kb = y * 8 + lane8;
        const int xs = xl ^ (kb & 15);     // XOR swizzle, bijective per kb
        uint4 R;
        R.x = (unsigned)f2bf(num[0] * inv) | ((unsigned)f2bf(num[1] * inv) << 16);
        R.y = (unsigned)f2bf(num[2] * inv) | ((unsigned)f2bf(num[3] * inv) << 16);
        R.z = (unsigned)f2bf(num[4] * inv) | ((unsigned)f2bf(num[5] * inv) << 16);
        R.w = (unsigned)f2bf(num[6] * inv) | ((unsigned)f2bf(num[7] * inv) << 16);
        *(uint4*)&redB[kb][xs][0] = R;
    }

    __syncthreads();

    // ---- Phase 2: MFMA  C[128,16] = W[128,512] * red[512,16] ----
    const int wave = t >> 6;        // 0..3 -> M rows [wave*32, +32)
    const int lane = t & 63;
    const int q    = lane >> 4;     // 0..3
    const int l16  = lane & 15;     // 0..15

    f32x4 acc0 = {0.f, 0.f, 0.f, 0.f};
    f32x4 acc1 = {0.f, 0.f, 0.f, 0.f};
    const unsigned short* wrow0 = Wb + (wave * 32 + l16) * KD_;

    #pragma unroll
    for (int ks = 0; ks < 16; ++ks) {
        const int kbase = ks * 32 + q * 8;
        const short8 a0 = *(const short8*)(wrow0 + kbase);
        const short8 a1 = *(const short8*)(wrow0 + 16 * KD_ + kbase);
        const int kb = ks * 4 + q;
        const int xs = l16 ^ (kb & 15);
        const short8 bfr = *(const short8*)&redB[kb][xs][0];
        acc0 = __builtin_amdgcn_mfma_f32_16x16x32_bf16(a0, bfr, acc0, 0, 0, 0);
        acc1 = __builtin_amdgcn_mfma_f32_16x16x32_bf16(a1, bfr, acc1, 0, 0, 0);
    }

    const int xg = x0 + l16;
    if (xg < XC_) {
        #pragma unroll
        for (int j = 0; j < 4; ++j) {
            const int o0 = wave * 32 + q * 4 + j;
            out[(o0 * ZC_ + z) * XC_ + xg] = acc0[j] + bias[o0];
            const int o1 = o0 + 16;
            out[(o1 * ZC_ + z) * XC_ + xg] = acc1[j] + bias[o1];
        }
    }
}

extern "C" void kernel_launch(void* const* d_in, const int* in_sizes, int n_in,
                              void* d_out, int out_size, void* d_ws, size_t ws_size,
                              hipStream_t stream) {
    const float* coords = (const float*)d_in[0];   // (1,4,200,8,200,3)
    const float* validm = (const float*)d_in[1];   // (1,4,200,8,200,1)
    const float* img    = (const float*)d_in[2];   // (1,4,64,28,60)
    const float* Wc     = (const float*)d_in[3];   // (128, 512)
    const float* bias   = (const float*)d_in[4];   // (128)
    float* out = (float*)d_out;                    // (1,1,128,200,200)

    unsigned short* featB = (unsigned short*)d_ws;           // 430080 bf16
    unsigned short* Wb    = featB + (N_ * H_ * W_ * C_);     // 65536 bf16

    gsvt_prep<<<512, 256, 0, stream>>>(img, Wc, featB, Wb);

    dim3 grid((XC_ + TX - 1) / TX, ZC_);
    gsvt_fused<<<grid, 256, 0, stream>>>(coords, validm, featB, Wb, bias, out);
}

// Round 3
// 75.605 us; speedup vs baseline: 4.8467x; 1.2329x over previous
//
#include <hip/hip_runtime.h>
#include <hip/hip_bf16.h>

#define N_  4
#define C_  64
#define H_  28
#define W_  60
#define ZC_ 200
#define YC_ 8
#define XC_ 200
#define OUTC_ 128
#define KD_ 512            // C_*YC_
#define EPS_ 1e-6f
#define TX 16              // x positions per block (one MFMA N-tile)

typedef __attribute__((ext_vector_type(8))) short short8;
typedef __attribute__((ext_vector_type(4))) float f32x4;

__device__ __forceinline__ unsigned short f2bf(float f) {
    unsigned int u = __float_as_uint(f);
    u += 0x7FFF + ((u >> 16) & 1);   // round-to-nearest-even
    return (unsigned short)(u >> 16);
}

// ---------------------------------------------------------------------------
// Prep: featB[n][h][w][c] = bf16(img[n][c][h][w])  (channels-last, bf16)
//       Wb[o][y*64+c]     = bf16(W[o][c*8+y])      (y-major k, bf16)
// ---------------------------------------------------------------------------
__global__ void gsvt_prep(const float* __restrict__ img,
                          const float* __restrict__ Wc,
                          unsigned short* __restrict__ featB,
                          unsigned short* __restrict__ Wb) {
    int tid = blockIdx.x * blockDim.x + threadIdx.x;
    int stride = gridDim.x * blockDim.x;
    const int totF = N_ * H_ * W_ * C_;       // 430080
    for (int i = tid; i < totF; i += stride) {
        int c  = i & 63;
        int hw = i >> 6;
        int w  = hw % W_;
        int nh = hw / W_;
        int h  = nh % H_;
        int n  = nh / H_;
        featB[i] = f2bf(img[((n * C_ + c) * H_ + h) * W_ + w]);
    }
    const int totW = OUTC_ * KD_;             // 65536
    for (int i = tid; i < totW; i += stride) {
        int k = i & (KD_ - 1);
        int o = i >> 9;
        int y = k >> 6;
        int c = k & 63;
        Wb[i] = f2bf(Wc[o * KD_ + c * YC_ + y]);
    }
}

__device__ __forceinline__ void acc8(float* num, const uint4 V, const float w) {
    num[0] += w * __uint_as_float(V.x << 16);
    num[1] += w * __uint_as_float(V.x & 0xFFFF0000u);
    num[2] += w * __uint_as_float(V.y << 16);
    num[3] += w * __uint_as_float(V.y & 0xFFFF0000u);
    num[4] += w * __uint_as_float(V.z << 16);
    num[5] += w * __uint_as_float(V.z & 0xFFFF0000u);
    num[6] += w * __uint_as_float(V.w << 16);
    num[7] += w * __uint_as_float(V.w & 0xFFFF0000u);
}

// ---------------------------------------------------------------------------
// Fused: weight precompute + sample + 512->128 MFMA matvec
// Grid: (ceil(XC/TX)=13, ZC), block 256
// ---------------------------------------------------------------------------
__global__ __launch_bounds__(256) void gsvt_fused(
        const float* __restrict__ coords,        // (N, ZC, YC, XC, 3)
        const float* __restrict__ validm,        // (N, ZC, YC, XC)
        const unsigned short* __restrict__ featB,// (N, H, W, C) bf16
        const unsigned short* __restrict__ Wb,   // (OUTC, 512) bf16, y-major k
        const float* __restrict__ bias,          // (OUTC)
        float* __restrict__ out)                 // (OUTC, ZC, XC)
{
    __shared__ float4 wq[512];                   // corner weights, 8 KB
    __shared__ uint2  oyy[512];                  // row byte-offsets, 4 KB
    __shared__ unsigned oxb[512];                // packed x byte-offsets, 2 KB
    __shared__ unsigned short redB[64][TX][8];   // k-blocked bf16, 16 KB
    float (*ms)[4] = (float(*)[4])&redB[0][0][0];  // aliased 2 KB (dead before redB use)

    const int z  = blockIdx.y;
    const int x0 = blockIdx.x * TX;
    const int t  = threadIdx.x;

    // ---- Phase 0a: load coords/mask. item = n*128 + pr, pr = y*16+xl.
    // thread t handles items t and t+256 (same pr, cams n0 and n0+2).
    const int pr = t & 127;
    const int py0 = pr >> 4, pxl0 = pr & 15;
    const int xg = min(x0 + pxl0, XC_ - 1);
    const int n0 = t >> 7;

    float gx[2], gy[2], gz[2], mm[2];
    #pragma unroll
    for (int ii = 0; ii < 2; ++ii) {
        const int n = n0 + ii * 2;
        const int cb = ((n * ZC_ + z) * YC_ + py0) * XC_ + xg;
        gx[ii] = coords[cb * 3 + 0];
        gy[ii] = coords[cb * 3 + 1];
        gz[ii] = coords[cb * 3 + 2];
        mm[ii] = validm[cb];
        ms[pr][n] = mm[ii];
    }
    __syncthreads();

    // ---- Phase 0b: weights (mask, z-weight, 1/den folded in) + offsets ----
    const float inv = 1.0f / (ms[pr][0] + ms[pr][1] + ms[pr][2] + ms[pr][3] + EPS_);
    #pragma unroll
    for (int ii = 0; ii < 2; ++ii) {
        const int n  = n0 + ii * 2;
        const int it = n * 128 + pr;

        const float xf = ((gx[ii] + 1.0f) * (float)W_ - 1.0f) * 0.5f;
        const float yf = ((gy[ii] + 1.0f) * (float)H_ - 1.0f) * 0.5f;
        const float zf = gz[ii] * 0.5f;
        const float x0f = floorf(xf), y0f = floorf(yf), z0f = floorf(zf);
        const float wx = xf - x0f, wy = yf - y0f, wz = zf - z0f;
        const int xi = (int)x0f, yi = (int)y0f, zi = (int)z0f;

        const float zw = (zi == 0) ? (1.f - wz) : ((zi == -1) ? wz : 0.f);
        const float s  = mm[ii] * zw * inv;

        const float wx0 = (xi >= 0 && xi < W_)         ? (1.f - wx) * s : 0.f;
        const float wx1 = (xi + 1 >= 0 && xi + 1 < W_) ? wx * s         : 0.f;
        const float wy0 = (yi >= 0 && yi < H_)         ? (1.f - wy)     : 0.f;
        const float wy1 = (yi + 1 >= 0 && yi + 1 < H_) ? wy             : 0.f;

        wq[it] = make_float4(wy0 * wx0, wy0 * wx1, wy1 * wx0, wy1 * wx1);

        const int xc0 = min(max(xi, 0), W_ - 1);
        const int xc1 = min(max(xi + 1, 0), W_ - 1);
        const int yc0 = min(max(yi, 0), H_ - 1);
        const int yc1 = min(max(yi + 1, 0), H_ - 1);
        oyy[it] = make_uint2((unsigned)(((n * H_ + yc0) * W_) * 128),
                             (unsigned)(((n * H_ + yc1) * W_) * 128));
        oxb[it] = (unsigned)(xc0 * 128) | ((unsigned)(xc1 * 128) << 16);
    }
    __syncthreads();

    // ---- Phase B: gather + weighted accumulate. 32 groups of 8 lanes. ----
    const int grp   = t >> 3;
    const int lane8 = t & 7;
    const unsigned lb = (unsigned)(lane8 << 4);
    const char* fb = (const char*)featB;

    #pragma unroll
    for (int i = 0; i < 4; ++i) {
        const int p   = grp + 32 * i;
        const int py  = p >> 4, pxl = p & 15;

        float num[8] = {0.f,0.f,0.f,0.f,0.f,0.f,0.f,0.f};

        #pragma unroll
        for (int n = 0; n < N_; ++n) {
            const int it = n * 128 + p;
            const float4 w4 = wq[it];
            const uint2 yy  = oyy[it];
            const unsigned xb = oxb[it];
            const unsigned xlo = xb & 0xFFFFu, xhi = xb >> 16;

            const uint4 V00 = *(const uint4*)(fb + (yy.x + xlo + lb));
            const uint4 V01 = *(const uint4*)(fb + (yy.x + xhi + lb));
            const uint4 V10 = *(const uint4*)(fb + (yy.y + xlo + lb));
            const uint4 V11 = *(const uint4*)(fb + (yy.y + xhi + lb));

            acc8(num, V00, w4.x);
            acc8(num, V01, w4.y);
            acc8(num, V10, w4.z);
            acc8(num, V11, w4.w);
        }

        // pack to bf16 pairs and write swizzled redB
        const int kb = py * 8 + lane8;
        const int xs = pxl ^ (kb & 15);
        unsigned r0, r1, r2, r3;
        asm("v_cvt_pk_bf16_f32 %0, %1, %2" : "=v"(r0) : "v"(num[0]), "v"(num[1]));
        asm("v_cvt_pk_bf16_f32 %0, %1, %2" : "=v"(r1) : "v"(num[2]), "v"(num[3]));
        asm("v_cvt_pk_bf16_f32 %0, %1, %2" : "=v"(r2) : "v"(num[4]), "v"(num[5]));
        asm("v_cvt_pk_bf16_f32 %0, %1, %2" : "=v"(r3) : "v"(num[6]), "v"(num[7]));
        *(uint4*)&redB[kb][xs][0] = make_uint4(r0, r1, r2, r3);
    }

    __syncthreads();

    // ---- Phase 2: MFMA  C[128,16] = W[128,512] * red[512,16] ----
    const int wave = t >> 6;        // 0..3 -> M rows [wave*32, +32)
    const int lane = t & 63;
    const int q    = lane >> 4;     // 0..3
    const int l16  = lane & 15;     // 0..15

    f32x4 acc0 = {0.f, 0.f, 0.f, 0.f};
    f32x4 acc1 = {0.f, 0.f, 0.f, 0.f};
    const unsigned short* wrow0 = Wb + (wave * 32 + l16) * KD_;

    #pragma unroll
    for (int ks = 0; ks < 16; ++ks) {
        const int kbase = ks * 32 + q * 8;
        const short8 a0 = *(const short8*)(wrow0 + kbase);
        const short8 a1 = *(const short8*)(wrow0 + 16 * KD_ + kbase);
        const int kb = ks * 4 + q;
        const int xs = l16 ^ (kb & 15);
        const short8 bfr = *(const short8*)&redB[kb][xs][0];
        acc0 = __builtin_amdgcn_mfma_f32_16x16x32_bf16(a0, bfr, acc0, 0, 0, 0);
        acc1 = __builtin_amdgcn_mfma_f32_16x16x32_bf16(a1, bfr, acc1, 0, 0, 0);
    }

    const int xg2 = x0 + l16;
    if (xg2 < XC_) {
        #pragma unroll
        for (int j = 0; j < 4; ++j) {
            const int o0 = wave * 32 + q * 4 + j;
            out[(o0 * ZC_ + z) * XC_ + xg2] = acc0[j] + bias[o0];
            const int o1 = o0 + 16;
            out[(o1 * ZC_ + z) * XC_ + xg2] = acc1[j] + bias[o1];
        }
    }
}

extern "C" void kernel_launch(void* const* d_in, const int* in_sizes, int n_in,
                              void* d_out, int out_size, void* d_ws, size_t ws_size,
                              hipStream_t stream) {
    const float* coords = (const float*)d_in[0];   // (1,4,200,8,200,3)
    const float* validm = (const float*)d_in[1];   // (1,4,200,8,200,1)
    const float* img    = (const float*)d_in[2];   // (1,4,64,28,60)
    const float* Wc     = (const float*)d_in[3];   // (128, 512)
    const float* bias   = (const float*)d_in[4];   // (128)
    float* out = (float*)d_out;                    // (1,1,128,200,200)

    unsigned short* featB = (unsigned short*)d_ws;           // 430080 bf16
    unsigned short* Wb    = featB + (N_ * H_ * W_ * C_);     // 65536 bf16

    gsvt_prep<<<512, 256, 0, stream>>>(img, Wc, featB, Wb);

    dim3 grid((XC_ + TX - 1) / TX, ZC_);
    gsvt_fused<<<grid, 256, 0, stream>>>(coords, validm, featB, Wb, bias, out);
}

// Round 4
// 74.865 us; speedup vs baseline: 4.8946x; 1.0099x over previous
//
#include <hip/hip_runtime.h>
#include <hip/hip_bf16.h>

#define N_  4
#define C_  64
#define H_  28
#define W_  60
#define ZC_ 200
#define YC_ 8
#define XC_ 200
#define OUTC_ 128
#define KD_ 512            // C_*YC_
#define EPS_ 1e-6f
#define TX 16              // x positions per block (one MFMA N-tile)

typedef __attribute__((ext_vector_type(8))) short short8;
typedef __attribute__((ext_vector_type(4))) float f32x4;

__device__ __forceinline__ unsigned short f2bf(float f) {
    unsigned int u = __float_as_uint(f);
    u += 0x7FFF + ((u >> 16) & 1);   // round-to-nearest-even
    return (unsigned short)(u >> 16);
}

// ---------------------------------------------------------------------------
// Prep: featB[n][h][w][c] = bf16(img[n][c][h][w])  (channels-last, bf16)
//       Wb[o][y*64+c]     = bf16(W[o][c*8+y])      (y-major k, bf16)
// ---------------------------------------------------------------------------
__global__ void gsvt_prep(const float* __restrict__ img,
                          const float* __restrict__ Wc,
                          unsigned short* __restrict__ featB,
                          unsigned short* __restrict__ Wb) {
    int tid = blockIdx.x * blockDim.x + threadIdx.x;
    int stride = gridDim.x * blockDim.x;
    const int totF = N_ * H_ * W_ * C_;       // 430080
    for (int i = tid; i < totF; i += stride) {
        int c  = i & 63;
        int hw = i >> 6;
        int w  = hw % W_;
        int nh = hw / W_;
        int h  = nh % H_;
        int n  = nh / H_;
        featB[i] = f2bf(img[((n * C_ + c) * H_ + h) * W_ + w]);
    }
    const int totW = OUTC_ * KD_;             // 65536
    for (int i = tid; i < totW; i += stride) {
        int k = i & (KD_ - 1);
        int o = i >> 9;
        int y = k >> 6;
        int c = k & 63;
        Wb[i] = f2bf(Wc[o * KD_ + c * YC_ + y]);
    }
}

__device__ __forceinline__ void acc8(float* num, const uint4 V, const float w) {
    num[0] += w * __uint_as_float(V.x << 16);
    num[1] += w * __uint_as_float(V.x & 0xFFFF0000u);
    num[2] += w * __uint_as_float(V.y << 16);
    num[3] += w * __uint_as_float(V.y & 0xFFFF0000u);
    num[4] += w * __uint_as_float(V.z << 16);
    num[5] += w * __uint_as_float(V.z & 0xFFFF0000u);
    num[6] += w * __uint_as_float(V.w << 16);
    num[7] += w * __uint_as_float(V.w & 0xFFFF0000u);
}

// ---------------------------------------------------------------------------
// Fused: weight precompute + sample + 512->128 MFMA matvec
// Grid: (ceil(XC/TX)=13, ZC), block 256
// ---------------------------------------------------------------------------
__global__ __launch_bounds__(256, 4) void gsvt_fused(
        const float* __restrict__ coords,        // (N, ZC, YC, XC, 3)
        const float* __restrict__ validm,        // (N, ZC, YC, XC)
        const unsigned short* __restrict__ featB,// (N, H, W, C) bf16
        const unsigned short* __restrict__ Wb,   // (OUTC, 512) bf16, y-major k
        const float* __restrict__ bias,          // (OUTC)
        float* __restrict__ out)                 // (OUTC, ZC, XC)
{
    __shared__ float4 wq[512];                   // corner weights, 8 KB
    __shared__ uint2  off[512];                  // (base, dx|dy<<16), 4 KB
    __shared__ unsigned short redB[64][TX][8];   // k-blocked bf16, 16 KB
    float (*ms)[4] = (float(*)[4])&redB[0][0][0];  // aliased 2 KB (dead before redB use)

    const int z  = blockIdx.y;
    const int x0 = blockIdx.x * TX;
    const int t  = threadIdx.x;

    // ---- Phase 0a: load coords/mask. item = n*128 + pr, pr = y*16+xl.
    const int pr = t & 127;
    const int py0 = pr >> 4, pxl0 = pr & 15;
    const int xg = min(x0 + pxl0, XC_ - 1);
    const int n0 = t >> 7;

    float gx[2], gy[2], gz[2], mm[2];
    #pragma unroll
    for (int ii = 0; ii < 2; ++ii) {
        const int n = n0 + ii * 2;
        const int cb = ((n * ZC_ + z) * YC_ + py0) * XC_ + xg;
        gx[ii] = coords[cb * 3 + 0];
        gy[ii] = coords[cb * 3 + 1];
        gz[ii] = coords[cb * 3 + 2];
        mm[ii] = validm[cb];
        ms[pr][n] = mm[ii];
    }
    __syncthreads();

    // ---- Phase 0b: weights (mask, z-weight, 1/den folded in) + offsets ----
    const float inv = 1.0f / (ms[pr][0] + ms[pr][1] + ms[pr][2] + ms[pr][3] + EPS_);
    #pragma unroll
    for (int ii = 0; ii < 2; ++ii) {
        const int n  = n0 + ii * 2;
        const int it = n * 128 + pr;

        const float xf = ((gx[ii] + 1.0f) * (float)W_ - 1.0f) * 0.5f;
        const float yf = ((gy[ii] + 1.0f) * (float)H_ - 1.0f) * 0.5f;
        const float zf = gz[ii] * 0.5f;
        const float x0f = floorf(xf), y0f = floorf(yf), z0f = floorf(zf);
        const float wx = xf - x0f, wy = yf - y0f, wz = zf - z0f;
        const int xi = (int)x0f, yi = (int)y0f, zi = (int)z0f;

        const float zw = (zi == 0) ? (1.f - wz) : ((zi == -1) ? wz : 0.f);
        const float s  = mm[ii] * zw * inv;

        const float wx0 = (xi >= 0 && xi < W_)         ? (1.f - wx) * s : 0.f;
        const float wx1 = (xi + 1 >= 0 && xi + 1 < W_) ? wx * s         : 0.f;
        const float wy0 = (yi >= 0 && yi < H_)         ? (1.f - wy)     : 0.f;
        const float wy1 = (yi + 1 >= 0 && yi + 1 < H_) ? wy             : 0.f;

        wq[it] = make_float4(wy0 * wx0, wy0 * wx1, wy1 * wx0, wy1 * wx1);

        const int xc0 = min(max(xi, 0), W_ - 1);
        const int xc1 = min(max(xi + 1, 0), W_ - 1);
        const int yc0 = min(max(yi, 0), H_ - 1);
        const int yc1 = min(max(yi + 1, 0), H_ - 1);
        const unsigned base = (unsigned)((((n * H_ + yc0) * W_) + xc0) * 128);
        const unsigned dx   = (unsigned)((xc1 - xc0) * 128);          // 0 or 128
        const unsigned dy   = (unsigned)((yc1 - yc0) * W_ * 128);     // 0 or 7680
        off[it] = make_uint2(base, dx | (dy << 16));
    }
    __syncthreads();

    // ---- Phase B: gather + weighted accumulate. 32 groups of 8 lanes. ----
    const int grp   = t >> 3;
    const int lane8 = t & 7;
    const unsigned lb = (unsigned)(lane8 << 4);
    const char* fb = (const char*)featB;

    #pragma unroll
    for (int i = 0; i < 4; ++i) {
        const int p   = grp + 32 * i;
        const int py  = p >> 4, pxl = p & 15;

        // 1) all weights + offsets from LDS (independent reads)
        float4 w4[4];
        uint2  oo[4];
        #pragma unroll
        for (int n = 0; n < N_; ++n) {
            w4[n] = wq[n * 128 + p];
            oo[n] = off[n * 128 + p];
        }

        // 2) all 16 corner loads in flight
        uint4 V[16];
        #pragma unroll
        for (int n = 0; n < N_; ++n) {
            const unsigned base = oo[n].x + lb;
            const unsigned dx = oo[n].y & 0xFFFFu;
            const unsigned dy = oo[n].y >> 16;
            V[n * 4 + 0] = *(const uint4*)(fb + base);
            V[n * 4 + 1] = *(const uint4*)(fb + (base + dx));
            V[n * 4 + 2] = *(const uint4*)(fb + (base + dy));
            V[n * 4 + 3] = *(const uint4*)(fb + (base + dy + dx));
        }

        // 3) weighted accumulate
        float num[8] = {0.f,0.f,0.f,0.f,0.f,0.f,0.f,0.f};
        #pragma unroll
        for (int n = 0; n < N_; ++n) {
            acc8(num, V[n * 4 + 0], w4[n].x);
            acc8(num, V[n * 4 + 1], w4[n].y);
            acc8(num, V[n * 4 + 2], w4[n].z);
            acc8(num, V[n * 4 + 3], w4[n].w);
        }

        // 4) pack to bf16 pairs and write swizzled redB
        const int kb = py * 8 + lane8;
        const int xs = pxl ^ (kb & 15);
        unsigned r0, r1, r2, r3;
        asm("v_cvt_pk_bf16_f32 %0, %1, %2" : "=v"(r0) : "v"(num[0]), "v"(num[1]));
        asm("v_cvt_pk_bf16_f32 %0, %1, %2" : "=v"(r1) : "v"(num[2]), "v"(num[3]));
        asm("v_cvt_pk_bf16_f32 %0, %1, %2" : "=v"(r2) : "v"(num[4]), "v"(num[5]));
        asm("v_cvt_pk_bf16_f32 %0, %1, %2" : "=v"(r3) : "v"(num[6]), "v"(num[7]));
        *(uint4*)&redB[kb][xs][0] = make_uint4(r0, r1, r2, r3);
    }

    __syncthreads();

    // ---- Phase 2: MFMA  C[128,16] = W[128,512] * red[512,16] ----
    const int wave = t >> 6;        // 0..3 -> M rows [wave*32, +32)
    const int lane = t & 63;
    const int q    = lane >> 4;     // 0..3
    const int l16  = lane & 15;     // 0..15

    f32x4 acc0 = {0.f, 0.f, 0.f, 0.f};
    f32x4 acc1 = {0.f, 0.f, 0.f, 0.f};
    const unsigned short* wrow0 = Wb + (wave * 32 + l16) * KD_;

    #pragma unroll
    for (int ks = 0; ks < 16; ++ks) {
        const int kbase = ks * 32 + q * 8;
        const short8 a0 = *(const short8*)(wrow0 + kbase);
        const short8 a1 = *(const short8*)(wrow0 + 16 * KD_ + kbase);
        const int kb = ks * 4 + q;
        const int xs = l16 ^ (kb & 15);
        const short8 bfr = *(const short8*)&redB[kb][xs][0];
        acc0 = __builtin_amdgcn_mfma_f32_16x16x32_bf16(a0, bfr, acc0, 0, 0, 0);
        acc1 = __builtin_amdgcn_mfma_f32_16x16x32_bf16(a1, bfr, acc1, 0, 0, 0);
    }

    const int xg2 = x0 + l16;
    if (xg2 < XC_) {
        #pragma unroll
        for (int j = 0; j < 4; ++j) {
            const int o0 = wave * 32 + q * 4 + j;
            out[(o0 * ZC_ + z) * XC_ + xg2] = acc0[j] + bias[o0];
            const int o1 = o0 + 16;
            out[(o1 * ZC_ + z) * XC_ + xg2] = acc1[j] + bias[o1];
        }
    }
}

extern "C" void kernel_launch(void* const* d_in, const int* in_sizes, int n_in,
                              void* d_out, int out_size, void* d_ws, size_t ws_size,
                              hipStream_t stream) {
    const float* coords = (const float*)d_in[0];   // (1,4,200,8,200,3)
    const float* validm = (const float*)d_in[1];   // (1,4,200,8,200,1)
    const float* img    = (const float*)d_in[2];   // (1,4,64,28,60)
    const float* Wc     = (const float*)d_in[3];   // (128, 512)
    const float* bias   = (const float*)d_in[4];   // (128)
    float* out = (float*)d_out;                    // (1,1,128,200,200)

    unsigned short* featB = (unsigned short*)d_ws;           // 430080 bf16
    unsigned short* Wb    = featB + (N_ * H_ * W_ * C_);     // 65536 bf16

    gsvt_prep<<<512, 256, 0, stream>>>(img, Wc, featB, Wb);

    dim3 grid((XC_ + TX - 1) / TX, ZC_);
    gsvt_fused<<<grid, 256, 0, stream>>>(coords, validm, featB, Wb, bias, out);
}

// Round 5
// 72.798 us; speedup vs baseline: 5.0336x; 1.0284x over previous
//
#include <hip/hip_runtime.h>
#include <hip/hip_bf16.h>

#define N_  4
#define C_  64
#define H_  28
#define W_  60
#define ZC_ 200
#define YC_ 8
#define XC_ 200
#define OUTC_ 128
#define KD_ 512            // C_*YC_
#define EPS_ 1e-6f
#define TX 16              // x positions per block
#define NPTS 40000         // ZC_*XC_
#define TPB_GEMM 4         // tiles per gemm block (625 * 4 = 2500 tiles)

typedef __attribute__((ext_vector_type(8))) short short8;
typedef __attribute__((ext_vector_type(4))) float f32x4;

__device__ __forceinline__ unsigned short f2bf(float f) {
    unsigned int u = __float_as_uint(f);
    u += 0x7FFF + ((u >> 16) & 1);   // round-to-nearest-even
    return (unsigned short)(u >> 16);
}

// ---------------------------------------------------------------------------
// Prep: featB[n][h][w][c] = bf16(img[n][c][h][w])  (channels-last, bf16)
//       Wb[o][y*64+c]     = bf16(W[o][c*8+y])      (y-major k, bf16)
// ---------------------------------------------------------------------------
__global__ void gsvt_prep(const float* __restrict__ img,
                          const float* __restrict__ Wc,
                          unsigned short* __restrict__ featB,
                          unsigned short* __restrict__ Wb) {
    int tid = blockIdx.x * blockDim.x + threadIdx.x;
    int stride = gridDim.x * blockDim.x;
    const int totF = N_ * H_ * W_ * C_;       // 430080
    for (int i = tid; i < totF; i += stride) {
        int c  = i & 63;
        int hw = i >> 6;
        int w  = hw % W_;
        int nh = hw / W_;
        int h  = nh % H_;
        int n  = nh / H_;
        featB[i] = f2bf(img[((n * C_ + c) * H_ + h) * W_ + w]);
    }
    const int totW = OUTC_ * KD_;             // 65536
    for (int i = tid; i < totW; i += stride) {
        int k = i & (KD_ - 1);
        int o = i >> 9;
        int y = k >> 6;
        int c = k & 63;
        Wb[i] = f2bf(Wc[o * KD_ + c * YC_ + y]);
    }
}

__device__ __forceinline__ void acc8(float* num, const uint4 V, const float w) {
    num[0] += w * __uint_as_float(V.x << 16);
    num[1] += w * __uint_as_float(V.x & 0xFFFF0000u);
    num[2] += w * __uint_as_float(V.y << 16);
    num[3] += w * __uint_as_float(V.y & 0xFFFF0000u);
    num[4] += w * __uint_as_float(V.z << 16);
    num[5] += w * __uint_as_float(V.z & 0xFFFF0000u);
    num[6] += w * __uint_as_float(V.w << 16);
    num[7] += w * __uint_as_float(V.w & 0xFFFF0000u);
}

// ===========================================================================
// Shared phase-0 helper (computes wq/off tables in LDS).  Used by both the
// split sampler and the fused fallback.
// ===========================================================================
__device__ __forceinline__ void phase0(const float* __restrict__ coords,
                                       const float* __restrict__ validm,
                                       float4* wq, uint2* off, float (*ms)[4],
                                       int z, int x0, int t) {
    const int pr = t & 127;
    const int py0 = pr >> 4, pxl0 = pr & 15;
    const int xg = min(x0 + pxl0, XC_ - 1);
    const int n0 = t >> 7;

    float gx[2], gy[2], gz[2], mm[2];
    #pragma unroll
    for (int ii = 0; ii < 2; ++ii) {
        const int n = n0 + ii * 2;
        const int cb = ((n * ZC_ + z) * YC_ + py0) * XC_ + xg;
        gx[ii] = coords[cb * 3 + 0];
        gy[ii] = coords[cb * 3 + 1];
        gz[ii] = coords[cb * 3 + 2];
        mm[ii] = validm[cb];
        ms[pr][n] = mm[ii];
    }
    __syncthreads();

    const float inv = 1.0f / (ms[pr][0] + ms[pr][1] + ms[pr][2] + ms[pr][3] + EPS_);
    #pragma unroll
    for (int ii = 0; ii < 2; ++ii) {
        const int n  = n0 + ii * 2;
        const int it = n * 128 + pr;

        const float xf = ((gx[ii] + 1.0f) * (float)W_ - 1.0f) * 0.5f;
        const float yf = ((gy[ii] + 1.0f) * (float)H_ - 1.0f) * 0.5f;
        const float zf = gz[ii] * 0.5f;
        const float x0f = floorf(xf), y0f = floorf(yf), z0f = floorf(zf);
        const float wx = xf - x0f, wy = yf - y0f, wz = zf - z0f;
        const int xi = (int)x0f, yi = (int)y0f, zi = (int)z0f;

        const float zw = (zi == 0) ? (1.f - wz) : ((zi == -1) ? wz : 0.f);
        const float s  = mm[ii] * zw * inv;

        const float wx0 = (xi >= 0 && xi < W_)         ? (1.f - wx) * s : 0.f;
        const float wx1 = (xi + 1 >= 0 && xi + 1 < W_) ? wx * s         : 0.f;
        const float wy0 = (yi >= 0 && yi < H_)         ? (1.f - wy)     : 0.f;
        const float wy1 = (yi + 1 >= 0 && yi + 1 < H_) ? wy             : 0.f;

        wq[it] = make_float4(wy0 * wx0, wy0 * wx1, wy1 * wx0, wy1 * wx1);

        const int xc0 = min(max(xi, 0), W_ - 1);
        const int xc1 = min(max(xi + 1, 0), W_ - 1);
        const int yc0 = min(max(yi, 0), H_ - 1);
        const int yc1 = min(max(yi + 1, 0), H_ - 1);
        const unsigned base = (unsigned)((((n * H_ + yc0) * W_) + xc0) * 128);
        const unsigned dx   = (unsigned)((xc1 - xc0) * 128);
        const unsigned dy   = (unsigned)((yc1 - yc0) * W_ * 128);
        off[it] = make_uint2(base, dx | (dy << 16));
    }
    __syncthreads();
}

// ===========================================================================
// SPLIT PATH kernel 1: sampler -> writes red[64][NPTS][8] bf16 to global
// Grid: (13, 200), block 256
// ===========================================================================
__global__ __launch_bounds__(256, 4) void gsvt_sample(
        const float* __restrict__ coords,
        const float* __restrict__ validm,
        const unsigned short* __restrict__ featB,
        unsigned short* __restrict__ red)
{
    __shared__ float4 wq[512];
    __shared__ uint2  off[512];
    __shared__ float  ms[128][4];

    const int z  = blockIdx.y;
    const int x0 = blockIdx.x * TX;
    const int t  = threadIdx.x;

    phase0(coords, validm, wq, off, ms, z, x0, t);

    const int grp   = t >> 3;
    const int lane8 = t & 7;
    const unsigned lb = (unsigned)(lane8 << 4);
    const char* fb = (const char*)featB;

    #pragma unroll
    for (int i = 0; i < 4; ++i) {
        const int p   = grp + 32 * i;
        const int py  = p >> 4, pxl = p & 15;

        float4 w4[4];
        uint2  oo[4];
        #pragma unroll
        for (int n = 0; n < N_; ++n) {
            w4[n] = wq[n * 128 + p];
            oo[n] = off[n * 128 + p];
        }

        // all 16 corner loads issued as one batch (sched_barrier pins them)
        uint4 V[16];
        #pragma unroll
        for (int n = 0; n < N_; ++n) {
            const unsigned base = oo[n].x + lb;
            const unsigned dx = oo[n].y & 0xFFFFu;
            const unsigned dy = oo[n].y >> 16;
            V[n * 4 + 0] = *(const uint4*)(fb + base);
            V[n * 4 + 1] = *(const uint4*)(fb + (base + dx));
            V[n * 4 + 2] = *(const uint4*)(fb + (base + dy));
            V[n * 4 + 3] = *(const uint4*)(fb + (base + dy + dx));
        }
        __builtin_amdgcn_sched_barrier(0);

        float num[8] = {0.f,0.f,0.f,0.f,0.f,0.f,0.f,0.f};
        #pragma unroll
        for (int n = 0; n < N_; ++n) {
            acc8(num, V[n * 4 + 0], w4[n].x);
            acc8(num, V[n * 4 + 1], w4[n].y);
            acc8(num, V[n * 4 + 2], w4[n].z);
            acc8(num, V[n * 4 + 3], w4[n].w);
        }

        unsigned r0, r1, r2, r3;
        asm("v_cvt_pk_bf16_f32 %0, %1, %2" : "=v"(r0) : "v"(num[0]), "v"(num[1]));
        asm("v_cvt_pk_bf16_f32 %0, %1, %2" : "=v"(r1) : "v"(num[2]), "v"(num[3]));
        asm("v_cvt_pk_bf16_f32 %0, %1, %2" : "=v"(r2) : "v"(num[4]), "v"(num[5]));
        asm("v_cvt_pk_bf16_f32 %0, %1, %2" : "=v"(r3) : "v"(num[6]), "v"(num[7]));

        const int kb  = py * 8 + lane8;
        const int xg2 = x0 + pxl;
        if (xg2 < XC_) {
            *(uint4*)(red + ((size_t)kb * NPTS + z * XC_ + xg2) * 8) =
                make_uint4(r0, r1, r2, r3);
        }
    }
}

// ===========================================================================
// SPLIT PATH kernel 2: C[128, NPTS] = Wb[128,512] * red[512, NPTS] + bias
// A register-resident per wave (rows wave*32..+32). Grid: 625 blocks x 256.
// ===========================================================================
__global__ __launch_bounds__(256, 2) void gsvt_gemm(
        const unsigned short* __restrict__ red,   // [64][NPTS][8]
        const unsigned short* __restrict__ Wb,    // [128][512]
        const float* __restrict__ bias,
        float* __restrict__ out)                  // [128][NPTS]
{
    const int t    = threadIdx.x;
    const int wave = t >> 6;
    const int lane = t & 63;
    const int q    = lane >> 4;
    const int l16  = lane & 15;

    // A fragments, register-resident (loaded once per block)
    short8 A0[16], A1[16];
    const unsigned short* wrow0 = Wb + (wave * 32 + l16) * KD_;
    #pragma unroll
    for (int ks = 0; ks < 16; ++ks) {
        A0[ks] = *(const short8*)(wrow0 + ks * 32 + q * 8);
        A1[ks] = *(const short8*)(wrow0 + 16 * KD_ + ks * 32 + q * 8);
    }
    float bs0[4], bs1[4];
    #pragma unroll
    for (int j = 0; j < 4; ++j) {
        bs0[j] = bias[wave * 32 + q * 4 + j];
        bs1[j] = bias[wave * 32 + q * 4 + j + 16];
    }

    for (int tt = 0; tt < TPB_GEMM; ++tt) {
        const int n0 = (blockIdx.x * TPB_GEMM + tt) * 16;

        short8 Bf[16];
        #pragma unroll
        for (int ks = 0; ks < 16; ++ks) {
            const int kb = ks * 4 + q;
            Bf[ks] = *(const short8*)(red + ((size_t)kb * NPTS + n0 + l16) * 8);
        }

        f32x4 acc0 = {0.f, 0.f, 0.f, 0.f};
        f32x4 acc1 = {0.f, 0.f, 0.f, 0.f};
        #pragma unroll
        for (int ks = 0; ks < 16; ++ks) {
            acc0 = __builtin_amdgcn_mfma_f32_16x16x32_bf16(A0[ks], Bf[ks], acc0, 0, 0, 0);
            acc1 = __builtin_amdgcn_mfma_f32_16x16x32_bf16(A1[ks], Bf[ks], acc1, 0, 0, 0);
        }

        #pragma unroll
        for (int j = 0; j < 4; ++j) {
            const int o0 = wave * 32 + q * 4 + j;
            out[(size_t)o0 * NPTS + n0 + l16] = acc0[j] + bs0[j];
            out[(size_t)(o0 + 16) * NPTS + n0 + l16] = acc1[j] + bs1[j];
        }
    }
}

// ===========================================================================
// FALLBACK: fused kernel (round-4 version) when ws too small for red
// ===========================================================================
__global__ __launch_bounds__(256, 4) void gsvt_fused(
        const float* __restrict__ coords,
        const float* __restrict__ validm,
        const unsigned short* __restrict__ featB,
        const unsigned short* __restrict__ Wb,
        const float* __restrict__ bias,
        float* __restrict__ out)
{
    __shared__ float4 wq[512];
    __shared__ uint2  off[512];
    __shared__ unsigned short redB[64][TX][8];
    float (*ms)[4] = (float(*)[4])&redB[0][0][0];

    const int z  = blockIdx.y;
    const int x0 = blockIdx.x * TX;
    const int t  = threadIdx.x;

    phase0(coords, validm, wq, off, ms, z, x0, t);

    const int grp   = t >> 3;
    const int lane8 = t & 7;
    const unsigned lb = (unsigned)(lane8 << 4);
    const char* fb = (const char*)featB;

    #pragma unroll
    for (int i = 0; i < 4; ++i) {
        const int p   = grp + 32 * i;
        const int py  = p >> 4, pxl = p & 15;

        float4 w4[4];
        uint2  oo[4];
        #pragma unroll
        for (int n = 0; n < N_; ++n) {
            w4[n] = wq[n * 128 + p];
            oo[n] = off[n * 128 + p];
        }

        uint4 V[16];
        #pragma unroll
        for (int n = 0; n < N_; ++n) {
            const unsigned base = oo[n].x + lb;
            const unsigned dx = oo[n].y & 0xFFFFu;
            const unsigned dy = oo[n].y >> 16;
            V[n * 4 + 0] = *(const uint4*)(fb + base);
            V[n * 4 + 1] = *(const uint4*)(fb + (base + dx));
            V[n * 4 + 2] = *(const uint4*)(fb + (base + dy));
            V[n * 4 + 3] = *(const uint4*)(fb + (base + dy + dx));
        }
        __builtin_amdgcn_sched_barrier(0);

        float num[8] = {0.f,0.f,0.f,0.f,0.f,0.f,0.f,0.f};
        #pragma unroll
        for (int n = 0; n < N_; ++n) {
            acc8(num, V[n * 4 + 0], w4[n].x);
            acc8(num, V[n * 4 + 1], w4[n].y);
            acc8(num, V[n * 4 + 2], w4[n].z);
            acc8(num, V[n * 4 + 3], w4[n].w);
        }

        const int kb = py * 8 + lane8;
        const int xs = pxl ^ (kb & 15);
        unsigned r0, r1, r2, r3;
        asm("v_cvt_pk_bf16_f32 %0, %1, %2" : "=v"(r0) : "v"(num[0]), "v"(num[1]));
        asm("v_cvt_pk_bf16_f32 %0, %1, %2" : "=v"(r1) : "v"(num[2]), "v"(num[3]));
        asm("v_cvt_pk_bf16_f32 %0, %1, %2" : "=v"(r2) : "v"(num[4]), "v"(num[5]));
        asm("v_cvt_pk_bf16_f32 %0, %1, %2" : "=v"(r3) : "v"(num[6]), "v"(num[7]));
        *(uint4*)&redB[kb][xs][0] = make_uint4(r0, r1, r2, r3);
    }

    __syncthreads();

    const int wave = t >> 6;
    const int lane = t & 63;
    const int q    = lane >> 4;
    const int l16  = lane & 15;

    f32x4 acc0 = {0.f, 0.f, 0.f, 0.f};
    f32x4 acc1 = {0.f, 0.f, 0.f, 0.f};
    const unsigned short* wrow0 = Wb + (wave * 32 + l16) * KD_;

    #pragma unroll
    for (int ks = 0; ks < 16; ++ks) {
        const int kbase = ks * 32 + q * 8;
        const short8 a0 = *(const short8*)(wrow0 + kbase);
        const short8 a1 = *(const short8*)(wrow0 + 16 * KD_ + kbase);
        const int kb = ks * 4 + q;
        const int xs = l16 ^ (kb & 15);
        const short8 bfr = *(const short8*)&redB[kb][xs][0];
        acc0 = __builtin_amdgcn_mfma_f32_16x16x32_bf16(a0, bfr, acc0, 0, 0, 0);
        acc1 = __builtin_amdgcn_mfma_f32_16x16x32_bf16(a1, bfr, acc1, 0, 0, 0);
    }

    const int xg2 = x0 + l16;
    if (xg2 < XC_) {
        #pragma unroll
        for (int j = 0; j < 4; ++j) {
            const int o0 = wave * 32 + q * 4 + j;
            out[(o0 * ZC_ + z) * XC_ + xg2] = acc0[j] + bias[o0];
            const int o1 = o0 + 16;
            out[(o1 * ZC_ + z) * XC_ + xg2] = acc1[j] + bias[o1];
        }
    }
}

extern "C" void kernel_launch(void* const* d_in, const int* in_sizes, int n_in,
                              void* d_out, int out_size, void* d_ws, size_t ws_size,
                              hipStream_t stream) {
    const float* coords = (const float*)d_in[0];   // (1,4,200,8,200,3)
    const float* validm = (const float*)d_in[1];   // (1,4,200,8,200,1)
    const float* img    = (const float*)d_in[2];   // (1,4,64,28,60)
    const float* Wc     = (const float*)d_in[3];   // (128, 512)
    const float* bias   = (const float*)d_in[4];   // (128)
    float* out = (float*)d_out;                    // (1,1,128,200,200)

    unsigned short* featB = (unsigned short*)d_ws;           // 430080 bf16
    unsigned short* Wb    = featB + (N_ * H_ * W_ * C_);     // 65536 bf16
    unsigned short* red   = Wb + (OUTC_ * KD_);              // 64*40000*8 bf16

    const size_t need = (size_t)(N_ * H_ * W_ * C_ + OUTC_ * KD_) * 2
                      + (size_t)64 * NPTS * 8 * 2;           // ~42 MB

    gsvt_prep<<<512, 256, 0, stream>>>(img, Wc, featB, Wb);

    dim3 grid((XC_ + TX - 1) / TX, ZC_);
    if (ws_size >= need) {
        gsvt_sample<<<grid, 256, 0, stream>>>(coords, validm, featB, red);
        gsvt_gemm<<<625, 256, 0, stream>>>(red, Wb, bias, out);
    } else {
        gsvt_fused<<<grid, 256, 0, stream>>>(coords, validm, featB, Wb, bias, out);
    }
}

// Round 6
// 71.569 us; speedup vs baseline: 5.1200x; 1.0172x over previous
//
#include <hip/hip_runtime.h>
#include <hip/hip_bf16.h>

#define N_  4
#define C_  64
#define H_  28
#define W_  60
#define ZC_ 200
#define YC_ 8
#define XC_ 200
#define OUTC_ 128
#define KD_ 512            // C_*YC_
#define EPS_ 1e-6f
#define TX 16              // x positions per block
#define NPTS 40000         // ZC_*XC_
#define TPB_GEMM 4         // tiles per gemm block (625 * 4 = 2500 tiles)

typedef __attribute__((ext_vector_type(8))) short short8;
typedef __attribute__((ext_vector_type(4))) float f32x4;

__device__ __forceinline__ unsigned short f2bf(float f) {
    unsigned int u = __float_as_uint(f);
    u += 0x7FFF + ((u >> 16) & 1);   // round-to-nearest-even
    return (unsigned short)(u >> 16);
}

// ---------------------------------------------------------------------------
// Prep: featB[n][h][w][c] = bf16(img[n][c][h][w])  (channels-last, bf16)
//       Wb[o][y*64+c]     = bf16(W[o][c*8+y])      (y-major k, bf16)
// ---------------------------------------------------------------------------
__global__ void gsvt_prep(const float* __restrict__ img,
                          const float* __restrict__ Wc,
                          unsigned short* __restrict__ featB,
                          unsigned short* __restrict__ Wb) {
    int tid = blockIdx.x * blockDim.x + threadIdx.x;
    int stride = gridDim.x * blockDim.x;
    const int totF = N_ * H_ * W_ * C_;       // 430080
    for (int i = tid; i < totF; i += stride) {
        int c  = i & 63;
        int hw = i >> 6;
        int w  = hw % W_;
        int nh = hw / W_;
        int h  = nh % H_;
        int n  = nh / H_;
        featB[i] = f2bf(img[((n * C_ + c) * H_ + h) * W_ + w]);
    }
    const int totW = OUTC_ * KD_;             // 65536
    for (int i = tid; i < totW; i += stride) {
        int k = i & (KD_ - 1);
        int o = i >> 9;
        int y = k >> 6;
        int c = k & 63;
        Wb[i] = f2bf(Wc[o * KD_ + c * YC_ + y]);
    }
}

__device__ __forceinline__ void acc8(float* num, const uint4 V, const float w) {
    num[0] += w * __uint_as_float(V.x << 16);
    num[1] += w * __uint_as_float(V.x & 0xFFFF0000u);
    num[2] += w * __uint_as_float(V.y << 16);
    num[3] += w * __uint_as_float(V.y & 0xFFFF0000u);
    num[4] += w * __uint_as_float(V.z << 16);
    num[5] += w * __uint_as_float(V.z & 0xFFFF0000u);
    num[6] += w * __uint_as_float(V.w << 16);
    num[7] += w * __uint_as_float(V.w & 0xFFFF0000u);
}

// ===========================================================================
// Shared phase-0 helper (computes wq/off tables in LDS).
// ===========================================================================
__device__ __forceinline__ void phase0(const float* __restrict__ coords,
                                       const float* __restrict__ validm,
                                       float4* wq, uint2* off, float (*ms)[4],
                                       int z, int x0, int t) {
    const int pr = t & 127;
    const int py0 = pr >> 4, pxl0 = pr & 15;
    const int xg = min(x0 + pxl0, XC_ - 1);
    const int n0 = t >> 7;

    float gx[2], gy[2], gz[2], mm[2];
    #pragma unroll
    for (int ii = 0; ii < 2; ++ii) {
        const int n = n0 + ii * 2;
        const int cb = ((n * ZC_ + z) * YC_ + py0) * XC_ + xg;
        gx[ii] = coords[cb * 3 + 0];
        gy[ii] = coords[cb * 3 + 1];
        gz[ii] = coords[cb * 3 + 2];
        mm[ii] = validm[cb];
        ms[pr][n] = mm[ii];
    }
    __syncthreads();

    const float inv = 1.0f / (ms[pr][0] + ms[pr][1] + ms[pr][2] + ms[pr][3] + EPS_);
    #pragma unroll
    for (int ii = 0; ii < 2; ++ii) {
        const int n  = n0 + ii * 2;
        const int it = n * 128 + pr;

        const float xf = ((gx[ii] + 1.0f) * (float)W_ - 1.0f) * 0.5f;
        const float yf = ((gy[ii] + 1.0f) * (float)H_ - 1.0f) * 0.5f;
        const float zf = gz[ii] * 0.5f;
        const float x0f = floorf(xf), y0f = floorf(yf), z0f = floorf(zf);
        const float wx = xf - x0f, wy = yf - y0f, wz = zf - z0f;
        const int xi = (int)x0f, yi = (int)y0f, zi = (int)z0f;

        const float zw = (zi == 0) ? (1.f - wz) : ((zi == -1) ? wz : 0.f);
        const float s  = mm[ii] * zw * inv;

        const float wx0 = (xi >= 0 && xi < W_)         ? (1.f - wx) * s : 0.f;
        const float wx1 = (xi + 1 >= 0 && xi + 1 < W_) ? wx * s         : 0.f;
        const float wy0 = (yi >= 0 && yi < H_)         ? (1.f - wy)     : 0.f;
        const float wy1 = (yi + 1 >= 0 && yi + 1 < H_) ? wy             : 0.f;

        wq[it] = make_float4(wy0 * wx0, wy0 * wx1, wy1 * wx0, wy1 * wx1);

        const int xc0 = min(max(xi, 0), W_ - 1);
        const int xc1 = min(max(xi + 1, 0), W_ - 1);
        const int yc0 = min(max(yi, 0), H_ - 1);
        const int yc1 = min(max(yi + 1, 0), H_ - 1);
        const unsigned base = (unsigned)((((n * H_ + yc0) * W_) + xc0) * 128);
        const unsigned dx   = (unsigned)((xc1 - xc0) * 128);
        const unsigned dy   = (unsigned)((yc1 - yc0) * W_ * 128);
        off[it] = make_uint2(base, dx | (dy << 16));
    }
    __syncthreads();
}

// ===========================================================================
// SPLIT PATH kernel 1: sampler -> writes red[64][NPTS][8] bf16 to global
// Grid: (13, 200), block 256.  Per-(pair,cam) skip when weight == 0.
// ===========================================================================
__global__ __launch_bounds__(256, 8) void gsvt_sample(
        const float* __restrict__ coords,
        const float* __restrict__ validm,
        const unsigned short* __restrict__ featB,
        unsigned short* __restrict__ red)
{
    __shared__ float4 wq[512];
    __shared__ uint2  off[512];
    __shared__ float  ms[128][4];

    const int z  = blockIdx.y;
    const int x0 = blockIdx.x * TX;
    const int t  = threadIdx.x;

    phase0(coords, validm, wq, off, ms, z, x0, t);

    const int grp   = t >> 3;
    const int lane8 = t & 7;
    const unsigned lb = (unsigned)(lane8 << 4);
    const char* fb = (const char*)featB;

    #pragma unroll
    for (int i = 0; i < 4; ++i) {
        const int p   = grp + 32 * i;
        const int py  = p >> 4, pxl = p & 15;

        float num[8] = {0.f,0.f,0.f,0.f,0.f,0.f,0.f,0.f};

        #pragma unroll
        for (int n = 0; n < N_; ++n) {
            const float4 w4 = wq[n * 128 + p];
            if (w4.x + w4.y + w4.z + w4.w > 0.f) {   // ~64% of items skip
                const uint2 oo = off[n * 128 + p];
                const unsigned base = oo.x + lb;
                const unsigned dx = oo.y & 0xFFFFu;
                const unsigned dy = oo.y >> 16;
                const uint4 V0 = *(const uint4*)(fb + base);
                const uint4 V1 = *(const uint4*)(fb + (base + dx));
                const uint4 V2 = *(const uint4*)(fb + (base + dy));
                const uint4 V3 = *(const uint4*)(fb + (base + dy + dx));
                acc8(num, V0, w4.x);
                acc8(num, V1, w4.y);
                acc8(num, V2, w4.z);
                acc8(num, V3, w4.w);
            }
        }

        unsigned r0, r1, r2, r3;
        asm("v_cvt_pk_bf16_f32 %0, %1, %2" : "=v"(r0) : "v"(num[0]), "v"(num[1]));
        asm("v_cvt_pk_bf16_f32 %0, %1, %2" : "=v"(r1) : "v"(num[2]), "v"(num[3]));
        asm("v_cvt_pk_bf16_f32 %0, %1, %2" : "=v"(r2) : "v"(num[4]), "v"(num[5]));
        asm("v_cvt_pk_bf16_f32 %0, %1, %2" : "=v"(r3) : "v"(num[6]), "v"(num[7]));

        const int kb  = py * 8 + lane8;
        const int xg2 = x0 + pxl;
        if (xg2 < XC_) {
            *(uint4*)(red + ((size_t)kb * NPTS + z * XC_ + xg2) * 8) =
                make_uint4(r0, r1, r2, r3);
        }
    }
}

// ===========================================================================
// SPLIT PATH kernel 2: C[128, NPTS] = Wb[128,512] * red[512, NPTS] + bias
// A register-resident per wave. Grid: 625 blocks x 256.
// ===========================================================================
__global__ __launch_bounds__(256, 2) void gsvt_gemm(
        const unsigned short* __restrict__ red,   // [64][NPTS][8]
        const unsigned short* __restrict__ Wb,    // [128][512]
        const float* __restrict__ bias,
        float* __restrict__ out)                  // [128][NPTS]
{
    const int t    = threadIdx.x;
    const int wave = t >> 6;
    const int lane = t & 63;
    const int q    = lane >> 4;
    const int l16  = lane & 15;

    short8 A0[16], A1[16];
    const unsigned short* wrow0 = Wb + (wave * 32 + l16) * KD_;
    #pragma unroll
    for (int ks = 0; ks < 16; ++ks) {
        A0[ks] = *(const short8*)(wrow0 + ks * 32 + q * 8);
        A1[ks] = *(const short8*)(wrow0 + 16 * KD_ + ks * 32 + q * 8);
    }
    float bs0[4], bs1[4];
    #pragma unroll
    for (int j = 0; j < 4; ++j) {
        bs0[j] = bias[wave * 32 + q * 4 + j];
        bs1[j] = bias[wave * 32 + q * 4 + j + 16];
    }

    for (int tt = 0; tt < TPB_GEMM; ++tt) {
        const int n0 = (blockIdx.x * TPB_GEMM + tt) * 16;

        short8 Bf[16];
        #pragma unroll
        for (int ks = 0; ks < 16; ++ks) {
            const int kb = ks * 4 + q;
            Bf[ks] = *(const short8*)(red + ((size_t)kb * NPTS + n0 + l16) * 8);
        }

        f32x4 acc0 = {0.f, 0.f, 0.f, 0.f};
        f32x4 acc1 = {0.f, 0.f, 0.f, 0.f};
        #pragma unroll
        for (int ks = 0; ks < 16; ++ks) {
            acc0 = __builtin_amdgcn_mfma_f32_16x16x32_bf16(A0[ks], Bf[ks], acc0, 0, 0, 0);
            acc1 = __builtin_amdgcn_mfma_f32_16x16x32_bf16(A1[ks], Bf[ks], acc1, 0, 0, 0);
        }

        #pragma unroll
        for (int j = 0; j < 4; ++j) {
            const int o0 = wave * 32 + q * 4 + j;
            out[(size_t)o0 * NPTS + n0 + l16] = acc0[j] + bs0[j];
            out[(size_t)(o0 + 16) * NPTS + n0 + l16] = acc1[j] + bs1[j];
        }
    }
}

// ===========================================================================
// FALLBACK: fused kernel when ws too small for red
// ===========================================================================
__global__ __launch_bounds__(256, 4) void gsvt_fused(
        const float* __restrict__ coords,
        const float* __restrict__ validm,
        const unsigned short* __restrict__ featB,
        const unsigned short* __restrict__ Wb,
        const float* __restrict__ bias,
        float* __restrict__ out)
{
    __shared__ float4 wq[512];
    __shared__ uint2  off[512];
    __shared__ unsigned short redB[64][TX][8];
    float (*ms)[4] = (float(*)[4])&redB[0][0][0];

    const int z  = blockIdx.y;
    const int x0 = blockIdx.x * TX;
    const int t  = threadIdx.x;

    phase0(coords, validm, wq, off, ms, z, x0, t);

    const int grp   = t >> 3;
    const int lane8 = t & 7;
    const unsigned lb = (unsigned)(lane8 << 4);
    const char* fb = (const char*)featB;

    #pragma unroll
    for (int i = 0; i < 4; ++i) {
        const int p   = grp + 32 * i;
        const int py  = p >> 4, pxl = p & 15;

        float num[8] = {0.f,0.f,0.f,0.f,0.f,0.f,0.f,0.f};

        #pragma unroll
        for (int n = 0; n < N_; ++n) {
            const float4 w4 = wq[n * 128 + p];
            if (w4.x + w4.y + w4.z + w4.w > 0.f) {
                const uint2 oo = off[n * 128 + p];
                const unsigned base = oo.x + lb;
                const unsigned dx = oo.y & 0xFFFFu;
                const unsigned dy = oo.y >> 16;
                const uint4 V0 = *(const uint4*)(fb + base);
                const uint4 V1 = *(const uint4*)(fb + (base + dx));
                const uint4 V2 = *(const uint4*)(fb + (base + dy));
                const uint4 V3 = *(const uint4*)(fb + (base + dy + dx));
                acc8(num, V0, w4.x);
                acc8(num, V1, w4.y);
                acc8(num, V2, w4.z);
                acc8(num, V3, w4.w);
            }
        }

        const int kb = py * 8 + lane8;
        const int xs = pxl ^ (kb & 15);
        unsigned r0, r1, r2, r3;
        asm("v_cvt_pk_bf16_f32 %0, %1, %2" : "=v"(r0) : "v"(num[0]), "v"(num[1]));
        asm("v_cvt_pk_bf16_f32 %0, %1, %2" : "=v"(r1) : "v"(num[2]), "v"(num[3]));
        asm("v_cvt_pk_bf16_f32 %0, %1, %2" : "=v"(r2) : "v"(num[4]), "v"(num[5]));
        asm("v_cvt_pk_bf16_f32 %0, %1, %2" : "=v"(r3) : "v"(num[6]), "v"(num[7]));
        *(uint4*)&redB[kb][xs][0] = make_uint4(r0, r1, r2, r3);
    }

    __syncthreads();

    const int wave = t >> 6;
    const int lane = t & 63;
    const int q    = lane >> 4;
    const int l16  = lane & 15;

    f32x4 acc0 = {0.f, 0.f, 0.f, 0.f};
    f32x4 acc1 = {0.f, 0.f, 0.f, 0.f};
    const unsigned short* wrow0 = Wb + (wave * 32 + l16) * KD_;

    #pragma unroll
    for (int ks = 0; ks < 16; ++ks) {
        const int kbase = ks * 32 + q * 8;
        const short8 a0 = *(const short8*)(wrow0 + kbase);
        const short8 a1 = *(const short8*)(wrow0 + 16 * KD_ + kbase);
        const int kb = ks * 4 + q;
        const int xs = l16 ^ (kb & 15);
        const short8 bfr = *(const short8*)&redB[kb][xs][0];
        acc0 = __builtin_amdgcn_mfma_f32_16x16x32_bf16(a0, bfr, acc0, 0, 0, 0);
        acc1 = __builtin_amdgcn_mfma_f32_16x16x32_bf16(a1, bfr, acc1, 0, 0, 0);
    }

    const int xg2 = x0 + l16;
    if (xg2 < XC_) {
        #pragma unroll
        for (int j = 0; j < 4; ++j) {
            const int o0 = wave * 32 + q * 4 + j;
            out[(o0 * ZC_ + z) * XC_ + xg2] = acc0[j] + bias[o0];
            const int o1 = o0 + 16;
            out[(o1 * ZC_ + z) * XC_ + xg2] = acc1[j] + bias[o1];
        }
    }
}

extern "C" void kernel_launch(void* const* d_in, const int* in_sizes, int n_in,
                              void* d_out, int out_size, void* d_ws, size_t ws_size,
                              hipStream_t stream) {
    const float* coords = (const float*)d_in[0];   // (1,4,200,8,200,3)
    const float* validm = (const float*)d_in[1];   // (1,4,200,8,200,1)
    const float* img    = (const float*)d_in[2];   // (1,4,64,28,60)
    const float* Wc     = (const float*)d_in[3];   // (128, 512)
    const float* bias   = (const float*)d_in[4];   // (128)
    float* out = (float*)d_out;                    // (1,1,128,200,200)

    unsigned short* featB = (unsigned short*)d_ws;           // 430080 bf16
    unsigned short* Wb    = featB + (N_ * H_ * W_ * C_);     // 65536 bf16
    unsigned short* red   = Wb + (OUTC_ * KD_);              // 64*40000*8 bf16

    const size_t need = (size_t)(N_ * H_ * W_ * C_ + OUTC_ * KD_) * 2
                      + (size_t)64 * NPTS * 8 * 2;           // ~42 MB

    gsvt_prep<<<512, 256, 0, stream>>>(img, Wc, featB, Wb);

    dim3 grid((XC_ + TX - 1) / TX, ZC_);
    if (ws_size >= need) {
        gsvt_sample<<<grid, 256, 0, stream>>>(coords, validm, featB, red);
        gsvt_gemm<<<625, 256, 0, stream>>>(red, Wb, bias, out);
    } else {
        gsvt_fused<<<grid, 256, 0, stream>>>(coords, validm, featB, Wb, bias, out);
    }
}